// Round 1
// baseline (883.773 us; speedup 1.0000x reference)
//
#include <hip/hip_runtime.h>

typedef __bf16 bf16;
typedef __attribute__((ext_vector_type(8))) __bf16 bf16x8;
typedef __attribute__((ext_vector_type(4))) __bf16 bf16x4;
typedef __attribute__((ext_vector_type(4))) float floatx4;

#define B_SZ 512
#define N_SZ 2048
#define DIN  784
#define DINP 800   // 784 padded to multiple of 32

// ---------------------------------------------------------------------------
// prep: x[512][784] -> xb[512][800] bf16 (zero pad), w_in[2048][784] -> w_inb
// ---------------------------------------------------------------------------
__global__ __launch_bounds__(256)
void prep_kernel(const float* __restrict__ x, const float* __restrict__ w_in,
                 bf16* __restrict__ xb, bf16* __restrict__ w_inb)
{
    int g = blockIdx.x * 256 + threadIdx.x;           // 512000 total groups of 4
    const int GPR = DINP / 4;                         // 200 groups per row
    const float* src; bf16* dst; int row, c;
    if (g < B_SZ * GPR) {
        row = g / GPR; c = g - row * GPR;
        src = x + (size_t)row * DIN;  dst = xb + (size_t)row * DINP;
    } else {
        int h = g - B_SZ * GPR;
        row = h / GPR; c = h - row * GPR;
        src = w_in + (size_t)row * DIN;  dst = w_inb + (size_t)row * DINP;
    }
    int k = c * 4;
    floatx4 v = (floatx4){0.f, 0.f, 0.f, 0.f};
    if (k < DIN) v = *(const floatx4*)(src + k);      // 784 % 4 == 0, aligned
    bf16x4 o;
    o[0] = (bf16)v[0]; o[1] = (bf16)v[1]; o[2] = (bf16)v[2]; o[3] = (bf16)v[3];
    *(bf16x4*)(dst + k) = o;
}

// ---------------------------------------------------------------------------
// GEMM: out[b,m] = sum_k A[b,k] * Bmat[m,k]   (NT, both K-major)
// MODE 0: Bmat = W*M fp32 (DAG layers), A = acts (j-major concat, stride 2048)
// MODE 1: Bmat = bf16 w_inb (input layer), A = xb, stride 800
// 128x128 tile, BK=32, 4 waves each 64x64 via 4x4 mfma_f32_16x16x32_bf16.
// blockIdx.z = K-chunk -> partial[s][512][2048] fp32
// ---------------------------------------------------------------------------
template<int MODE>
__global__ __launch_bounds__(256, 2)
void gemm_kernel(const bf16* __restrict__ A,
                 const float* __restrict__ Wp, const float* __restrict__ Mp,
                 const bf16* __restrict__ Bbf,
                 float* __restrict__ partial,
                 int chunkK, int Ktot)
{
    __shared__ bf16 As[128 * 40];   // pad 32->40: 80B row stride, 16B aligned
    __shared__ bf16 Bs[128 * 40];

    const int t    = threadIdx.x;
    const int lane = t & 63, wave = t >> 6;
    const int wm   = (wave & 1) * 64, wn = (wave >> 1) * 64;
    const int l15  = lane & 15, quad = lane >> 4;
    const int n0   = blockIdx.x * 128, m0 = blockIdx.y * 128;
    const int s    = blockIdx.z;
    const int kb   = s * chunkK;
    const int ke   = (kb + chunkK < Ktot) ? (kb + chunkK) : Ktot;

    floatx4 acc[4][4];
#pragma unroll
    for (int a = 0; a < 4; a++)
#pragma unroll
        for (int b = 0; b < 4; b++) acc[a][b] = (floatx4){0.f, 0.f, 0.f, 0.f};

    for (int k0 = kb; k0 < ke; k0 += 32) {
        const bf16* Ab; const float *Wb = nullptr, *Mb = nullptr; const bf16* Bb = nullptr;
        if (MODE == 0) {
            int jj = k0 >> 11, nk = k0 & 2047;        // BK tile never crosses j
            Ab = A + (size_t)jj * (B_SZ * N_SZ) + (size_t)m0 * N_SZ + nk;
            size_t wo = (size_t)jj * N_SZ * N_SZ + (size_t)n0 * N_SZ + nk;
            Wb = Wp + wo;  Mb = Mp + wo;
        } else {
            Ab = A + (size_t)m0 * DINP + k0;
            Bb = Bbf + (size_t)n0 * DINP + k0;
        }
        __syncthreads();
        // ---- stage A tile: 128 rows x 32 k, bf16 ----
#pragma unroll
        for (int l = 0; l < 2; l++) {
            int q = l * 256 + t, row = q >> 2, seg = q & 3;
            const int lda = (MODE == 0) ? N_SZ : DINP;
            bf16x8 v = *(const bf16x8*)(Ab + (size_t)row * lda + seg * 8);
            *(bf16x8*)(&As[row * 40 + seg * 8]) = v;
        }
        // ---- stage B tile: 128 rows x 32 k ----
        if (MODE == 0) {
#pragma unroll
            for (int l = 0; l < 4; l++) {
                int f = l * 256 + t, row = f >> 3, kk = (f & 7) * 4;
                floatx4 w = *(const floatx4*)(Wb + (size_t)row * N_SZ + kk);
                floatx4 m = *(const floatx4*)(Mb + (size_t)row * N_SZ + kk);
                bf16x4 o;
                o[0] = (bf16)(w[0] * m[0]); o[1] = (bf16)(w[1] * m[1]);
                o[2] = (bf16)(w[2] * m[2]); o[3] = (bf16)(w[3] * m[3]);
                *(bf16x4*)(&Bs[row * 40 + kk]) = o;
            }
        } else {
#pragma unroll
            for (int l = 0; l < 2; l++) {
                int q = l * 256 + t, row = q >> 2, seg = q & 3;
                bf16x8 v = *(const bf16x8*)(Bb + (size_t)row * DINP + seg * 8);
                *(bf16x8*)(&Bs[row * 40 + seg * 8]) = v;
            }
        }
        __syncthreads();
        // ---- fragments + MFMA ----
        bf16x8 af[4], bfr[4];
#pragma unroll
        for (int a = 0; a < 4; a++)
            af[a] = *(const bf16x8*)(&As[(wm + a * 16 + l15) * 40 + quad * 8]);
#pragma unroll
        for (int b = 0; b < 4; b++)
            bfr[b] = *(const bf16x8*)(&Bs[(wn + b * 16 + l15) * 40 + quad * 8]);
#pragma unroll
        for (int a = 0; a < 4; a++)
#pragma unroll
            for (int b = 0; b < 4; b++)
                acc[a][b] = __builtin_amdgcn_mfma_f32_16x16x32_bf16(af[a], bfr[b], acc[a][b], 0, 0, 0);
    }

    // ---- write fp32 partial: C/D layout col=lane&15, row=quad*4+reg ----
    float* outp = partial + (size_t)s * (B_SZ * N_SZ);
#pragma unroll
    for (int a = 0; a < 4; a++)
#pragma unroll
        for (int b = 0; b < 4; b++)
#pragma unroll
            for (int r = 0; r < 4; r++) {
                int row = m0 + wm + a * 16 + quad * 4 + r;
                int col = n0 + wn + b * 16 + l15;
                outp[(size_t)row * N_SZ + col] = acc[a][b][r];
            }
}

// ---------------------------------------------------------------------------
// epilogue: act = bf16(relu(sum_s partial[s] + bscale * bias[n]))
// ---------------------------------------------------------------------------
__global__ __launch_bounds__(256)
void epilogue_kernel(const float* __restrict__ partial, int S,
                     const float* __restrict__ bias, float bscale,
                     bf16* __restrict__ act)
{
    int g = blockIdx.x * 256 + threadIdx.x;           // 262144 groups of 4
    size_t off = (size_t)g * 4;
    int n = (int)(off & (N_SZ - 1));
    floatx4 v = *(const floatx4*)(partial + off);
    for (int s2 = 1; s2 < S; s2++)
        v += *(const floatx4*)(partial + (size_t)s2 * (B_SZ * N_SZ) + off);
    floatx4 bv = *(const floatx4*)(bias + n);
    bf16x4 o;
#pragma unroll
    for (int j = 0; j < 4; j++) {
        float xv = v[j] + bscale * bv[j];
        xv = xv > 0.f ? xv : 0.f;
        o[j] = (bf16)xv;
    }
    *(bf16x4*)(act + off) = o;
}

// ---------------------------------------------------------------------------
// output: out[b,c] = act5[b]·w1[c] + b1[c] + act4[b]·w2[c] + b2[c]
// one wave per batch row
// ---------------------------------------------------------------------------
__global__ __launch_bounds__(64)
void out_kernel(const bf16* __restrict__ act4, const bf16* __restrict__ act5,
                const float* __restrict__ w1, const float* __restrict__ b1,
                const float* __restrict__ w2, const float* __restrict__ b2,
                float* __restrict__ out)
{
    int b = blockIdx.x, lane = threadIdx.x;
    float a5[32], a4[32];
#pragma unroll
    for (int rep = 0; rep < 4; rep++) {
        bf16x8 v5 = *(const bf16x8*)(act5 + (size_t)b * N_SZ + rep * 512 + lane * 8);
        bf16x8 v4 = *(const bf16x8*)(act4 + (size_t)b * N_SZ + rep * 512 + lane * 8);
#pragma unroll
        for (int j = 0; j < 8; j++) {
            a5[rep * 8 + j] = (float)v5[j];
            a4[rep * 8 + j] = (float)v4[j];
        }
    }
    for (int c = 0; c < 10; c++) {
        float d = 0.f;
#pragma unroll
        for (int rep = 0; rep < 4; rep++) {
            floatx4 wa = *(const floatx4*)(w1 + (size_t)c * N_SZ + rep * 512 + lane * 8);
            floatx4 wb = *(const floatx4*)(w1 + (size_t)c * N_SZ + rep * 512 + lane * 8 + 4);
            floatx4 va = *(const floatx4*)(w2 + (size_t)c * N_SZ + rep * 512 + lane * 8);
            floatx4 vb = *(const floatx4*)(w2 + (size_t)c * N_SZ + rep * 512 + lane * 8 + 4);
#pragma unroll
            for (int j = 0; j < 4; j++) {
                d += a5[rep * 8 + j] * wa[j] + a4[rep * 8 + j] * va[j];
                d += a5[rep * 8 + 4 + j] * wb[j] + a4[rep * 8 + 4 + j] * vb[j];
            }
        }
        for (int off = 32; off > 0; off >>= 1) d += __shfl_down(d, off);
        if (lane == 0) out[b * 10 + c] = d + b1[c] + b2[c];
    }
}

// ---------------------------------------------------------------------------
extern "C" void kernel_launch(void* const* d_in, const int* in_sizes, int n_in,
                              void* d_out, int out_size, void* d_ws, size_t ws_size,
                              hipStream_t stream)
{
    const float* x    = (const float*)d_in[0];
    const float* w_in = (const float*)d_in[1];
    const float* b_in = (const float*)d_in[2];
    const float* W    = (const float*)d_in[3];
    const float* M    = (const float*)d_in[4];
    const float* bL   = (const float*)d_in[5];
    const float* w1   = (const float*)d_in[6];
    const float* b1   = (const float*)d_in[7];
    const float* w2   = (const float*)d_in[8];
    const float* b2   = (const float*)d_in[9];
    float* out = (float*)d_out;

    // workspace layout (16B aligned):
    //   xb    : 512*800*2      =   819200
    //   w_inb : 2048*800*2     =  3276800
    //   acts  : 6*512*2048*2   = 12582912
    //   partial: 4*512*2048*4  = 16777216   (total ~33.5 MB)
    char* ws = (char*)d_ws;
    bf16*  xb      = (bf16*)ws;
    bf16*  w_inb   = (bf16*)(ws + 819200);
    bf16*  acts    = (bf16*)(ws + 4096000);
    float* partial = (float*)(ws + 16678912);

    prep_kernel<<<2000, 256, 0, stream>>>(x, w_in, xb, w_inb);

    // input layer: K=800, single chunk
    gemm_kernel<1><<<dim3(16, 4, 1), 256, 0, stream>>>(
        xb, nullptr, nullptr, w_inb, partial, DINP, DINP);
    epilogue_kernel<<<1024, 256, 0, stream>>>(partial, 1, b_in, 1.0f, acts);

    // DAG layers: K = 2048*i, 4 K-chunks -> 256 blocks per layer
    int idx = 0;
    for (int i = 1; i < 6; i++) {
        const float* Wp = W + (size_t)idx * N_SZ * N_SZ;
        const float* Mp = M + (size_t)idx * N_SZ * N_SZ;
        gemm_kernel<0><<<dim3(16, 4, 4), 256, 0, stream>>>(
            acts, Wp, Mp, nullptr, partial, 512 * i, 2048 * i);
        epilogue_kernel<<<1024, 256, 0, stream>>>(
            partial, 4, bL + (size_t)(i - 1) * N_SZ, (float)i,
            acts + (size_t)i * B_SZ * N_SZ);
        idx += i;
    }

    out_kernel<<<512, 64, 0, stream>>>(
        acts + (size_t)4 * B_SZ * N_SZ, acts + (size_t)5 * B_SZ * N_SZ,
        w1, b1, w2, b2, out);
}

// Round 2
// 715.340 us; speedup vs baseline: 1.2355x; 1.2355x over previous
//
#include <hip/hip_runtime.h>

typedef __bf16 bf16;
typedef __attribute__((ext_vector_type(8))) __bf16 bf16x8;
typedef __attribute__((ext_vector_type(4))) __bf16 bf16x4;
typedef __attribute__((ext_vector_type(4))) float floatx4;

#define B_SZ 512
#define N_SZ 2048
#define DIN  784
#define DINP 800      // 784 padded to multiple of 32
#define ACT_LD 12288  // actsT row stride: 6 slices x 2048

// async global->LDS, 16B per lane; LDS dest must be wave-uniform base (+lane*16)
__device__ __forceinline__ void load_lds16(const bf16* g, bf16* l) {
    __builtin_amdgcn_global_load_lds(
        (const __attribute__((address_space(1))) void*)g,
        (__attribute__((address_space(3))) void*)l, 16, 0, 0);
}

// ---------------------------------------------------------------------------
// prep: x[512][784] -> xb[512][800] bf16 (zero pad), w_in[2048][784] -> w_inb
// ---------------------------------------------------------------------------
__global__ __launch_bounds__(256)
void prep_kernel(const float* __restrict__ x, const float* __restrict__ w_in,
                 bf16* __restrict__ xb, bf16* __restrict__ w_inb)
{
    int g = blockIdx.x * 256 + threadIdx.x;           // 512000 groups of 4
    const int GPR = DINP / 4;                         // 200 groups per row
    const float* src; bf16* dst; int row, c;
    if (g < B_SZ * GPR) {
        row = g / GPR; c = g - row * GPR;
        src = x + (size_t)row * DIN;  dst = xb + (size_t)row * DINP;
    } else {
        int h = g - B_SZ * GPR;
        row = h / GPR; c = h - row * GPR;
        src = w_in + (size_t)row * DIN;  dst = w_inb + (size_t)row * DINP;
    }
    int k = c * 4;
    floatx4 v = (floatx4){0.f, 0.f, 0.f, 0.f};
    if (k < DIN) v = *(const floatx4*)(src + k);      // 784 % 4 == 0
    bf16x4 o;
    o[0] = (bf16)v[0]; o[1] = (bf16)v[1]; o[2] = (bf16)v[2]; o[3] = (bf16)v[3];
    *(bf16x4*)(dst + k) = o;
}

// ---------------------------------------------------------------------------
// wm: Wm_bf16 = W * M, re-laid out layer-major K-contiguous:
//   layer i (i=1..5) owns pairs p in [idx_i, idx_i+i), idx_i = i(i-1)/2
//   dest matrix for layer i: [2048 rows(m)] x [2048*i cols(k)], col = j*2048+kk
//   layer base (elements) = idx_i * 4M
// ---------------------------------------------------------------------------
__global__ __launch_bounds__(256)
void wm_kernel(const float* __restrict__ W, const float* __restrict__ M,
               bf16* __restrict__ Wm)
{
    int g = blockIdx.x * 256 + threadIdx.x;  // 15 * 2^20 threads, 4 elems each
    int p  = g >> 20;                        // pair index, block-uniform
    int n  = (g >> 9) & 2047;                // row within pair
    int k4 = (g & 511) * 4;                  // col within pair
    size_t so = ((size_t)p << 22) + ((size_t)n << 11) + k4;
    floatx4 w = *(const floatx4*)(W + so);
    floatx4 m = *(const floatx4*)(M + so);
    int i   = (p >= 10) ? 5 : (p >= 6) ? 4 : (p >= 3) ? 3 : (p >= 1) ? 2 : 1;
    int idx = i * (i - 1) / 2;
    int j   = p - idx;
    size_t dof = ((size_t)idx << 22) + (size_t)n * (N_SZ * i) + (size_t)j * N_SZ + k4;
    bf16x4 o;
    o[0] = (bf16)(w[0] * m[0]); o[1] = (bf16)(w[1] * m[1]);
    o[2] = (bf16)(w[2] * m[2]); o[3] = (bf16)(w[3] * m[3]);
    *(bf16x4*)(Wm + dof) = o;
}

// ---------------------------------------------------------------------------
// GEMM (m97 structure): out[b,m] = sum_k A[b,k]*Bm[m,k], both bf16 K-major.
// 128x128 tile, BK=32, 4 waves x (64x64 via 4x4 mfma_f32_16x16x32_bf16).
// Unpadded 128x32 LDS tiles staged with global_load_lds width 16.
// blockIdx.z = K-chunk -> partial[s][512][2048] fp32.
// ---------------------------------------------------------------------------
__global__ __launch_bounds__(256, 2)
void gemm_kernel(const bf16* __restrict__ A, int lda,
                 const bf16* __restrict__ Bm, int ldb,
                 float* __restrict__ partial,
                 int chunkK, int Ktot)
{
    __shared__ bf16 As[128 * 32];
    __shared__ bf16 Bs[128 * 32];

    const int t    = threadIdx.x;
    const int lane = t & 63, wave = t >> 6;
    const int wm   = (wave & 1) * 64, wn = (wave >> 1) * 64;
    const int l15  = lane & 15, quad = lane >> 4;
    const int n0   = blockIdx.x * 128, m0 = blockIdx.y * 128;
    const int s    = blockIdx.z;
    const int kb   = s * chunkK;
    const int ke   = (kb + chunkK < Ktot) ? (kb + chunkK) : Ktot;

    // staging: wave w fills LDS chunks w and w+4 (each 16 rows x 32 k = 1 KB)
    const int rA = wave * 16 + (lane >> 2);   // row within tile
    const int cA = (lane & 3) * 8;            // k-offset (8 bf16 = 16 B)
    const bf16* pA0 = A  + (size_t)(m0 + rA) * lda + cA + kb;
    const bf16* pA1 = pA0 + (size_t)64 * lda;
    const bf16* pB0 = Bm + (size_t)(n0 + rA) * ldb + cA + kb;
    const bf16* pB1 = pB0 + (size_t)64 * ldb;
    bf16* dA0 = &As[wave * 512];  bf16* dA1 = &As[(wave + 4) * 512];
    bf16* dB0 = &Bs[wave * 512];  bf16* dB1 = &Bs[(wave + 4) * 512];

    floatx4 acc[4][4];
#pragma unroll
    for (int a = 0; a < 4; a++)
#pragma unroll
        for (int b = 0; b < 4; b++) acc[a][b] = (floatx4){0.f, 0.f, 0.f, 0.f};

    for (int k0 = kb; k0 < ke; k0 += 32) {
        __syncthreads();
        load_lds16(pA0, dA0);  load_lds16(pA1, dA1);
        load_lds16(pB0, dB0);  load_lds16(pB1, dB1);
        pA0 += 32; pA1 += 32; pB0 += 32; pB1 += 32;
        __syncthreads();

        bf16x8 af[4], bfr[4];
#pragma unroll
        for (int a = 0; a < 4; a++)
            af[a] = *(const bf16x8*)(&As[(wm + a * 16 + l15) * 32 + quad * 8]);
#pragma unroll
        for (int b = 0; b < 4; b++)
            bfr[b] = *(const bf16x8*)(&Bs[(wn + b * 16 + l15) * 32 + quad * 8]);
#pragma unroll
        for (int a = 0; a < 4; a++)
#pragma unroll
            for (int b = 0; b < 4; b++)
                acc[a][b] = __builtin_amdgcn_mfma_f32_16x16x32_bf16(af[a], bfr[b], acc[a][b], 0, 0, 0);
    }

    // C/D layout: col = lane&15, row = quad*4 + reg
    float* outp = partial + (size_t)s * (B_SZ * N_SZ);
#pragma unroll
    for (int a = 0; a < 4; a++)
#pragma unroll
        for (int b = 0; b < 4; b++)
#pragma unroll
            for (int r = 0; r < 4; r++) {
                int row = m0 + wm + a * 16 + quad * 4 + r;
                int col = n0 + wn + b * 16 + l15;
                outp[(size_t)row * N_SZ + col] = acc[a][b][r];
            }
}

// ---------------------------------------------------------------------------
// epilogue: actsT[b][slice*2048+n] = bf16(relu(sum_s partial[s][b][n] + bscale*bias[n]))
// ---------------------------------------------------------------------------
__global__ __launch_bounds__(256)
void epilogue_kernel(const float* __restrict__ partial, int S,
                     const float* __restrict__ bias, float bscale,
                     bf16* __restrict__ actdst)   // = actsT + slice*2048
{
    int g = blockIdx.x * 256 + threadIdx.x;       // 262144 groups of 4
    size_t off = (size_t)g * 4;
    int b = (int)(off >> 11);
    int n = (int)(off & (N_SZ - 1));
    floatx4 v = *(const floatx4*)(partial + off);
    for (int s2 = 1; s2 < S; s2++)
        v += *(const floatx4*)(partial + (size_t)s2 * (B_SZ * N_SZ) + off);
    floatx4 bv = *(const floatx4*)(bias + n);
    bf16x4 o;
#pragma unroll
    for (int j = 0; j < 4; j++) {
        float xv = v[j] + bscale * bv[j];
        xv = xv > 0.f ? xv : 0.f;
        o[j] = (bf16)xv;
    }
    *(bf16x4*)(actdst + (size_t)b * ACT_LD + n) = o;
}

// ---------------------------------------------------------------------------
// output: out[b,c] = act5[b]·w1[c] + b1[c] + act4[b]·w2[c] + b2[c]
// act4/act5 are actsT column slices, row stride ACT_LD
// ---------------------------------------------------------------------------
__global__ __launch_bounds__(64)
void out_kernel(const bf16* __restrict__ act4, const bf16* __restrict__ act5,
                const float* __restrict__ w1, const float* __restrict__ b1,
                const float* __restrict__ w2, const float* __restrict__ b2,
                float* __restrict__ out)
{
    int b = blockIdx.x, lane = threadIdx.x;
    float a5[32], a4[32];
#pragma unroll
    for (int rep = 0; rep < 4; rep++) {
        bf16x8 v5 = *(const bf16x8*)(act5 + (size_t)b * ACT_LD + rep * 512 + lane * 8);
        bf16x8 v4 = *(const bf16x8*)(act4 + (size_t)b * ACT_LD + rep * 512 + lane * 8);
#pragma unroll
        for (int j = 0; j < 8; j++) {
            a5[rep * 8 + j] = (float)v5[j];
            a4[rep * 8 + j] = (float)v4[j];
        }
    }
    for (int c = 0; c < 10; c++) {
        float d = 0.f;
#pragma unroll
        for (int rep = 0; rep < 4; rep++) {
            floatx4 wa = *(const floatx4*)(w1 + (size_t)c * N_SZ + rep * 512 + lane * 8);
            floatx4 wb = *(const floatx4*)(w1 + (size_t)c * N_SZ + rep * 512 + lane * 8 + 4);
            floatx4 va = *(const floatx4*)(w2 + (size_t)c * N_SZ + rep * 512 + lane * 8);
            floatx4 vb = *(const floatx4*)(w2 + (size_t)c * N_SZ + rep * 512 + lane * 8 + 4);
#pragma unroll
            for (int j = 0; j < 4; j++) {
                d += a5[rep * 8 + j] * wa[j] + a4[rep * 8 + j] * va[j];
                d += a5[rep * 8 + 4 + j] * wb[j] + a4[rep * 8 + 4 + j] * vb[j];
            }
        }
        for (int off = 32; off > 0; off >>= 1) d += __shfl_down(d, off);
        if (lane == 0) out[b * 10 + c] = d + b1[c] + b2[c];
    }
}

// ---------------------------------------------------------------------------
extern "C" void kernel_launch(void* const* d_in, const int* in_sizes, int n_in,
                              void* d_out, int out_size, void* d_ws, size_t ws_size,
                              hipStream_t stream)
{
    const float* x    = (const float*)d_in[0];
    const float* w_in = (const float*)d_in[1];
    const float* b_in = (const float*)d_in[2];
    const float* W    = (const float*)d_in[3];
    const float* M    = (const float*)d_in[4];
    const float* bL   = (const float*)d_in[5];
    const float* w1   = (const float*)d_in[6];
    const float* b1   = (const float*)d_in[7];
    const float* w2   = (const float*)d_in[8];
    const float* b2   = (const float*)d_in[9];
    float* out = (float*)d_out;

    // workspace layout (all 16B-aligned):
    //   xb     @ 0        : 512*800*2    =    819200
    //   w_inb  @ 819200   : 2048*800*2   =   3276800
    //   actsT  @ 4096000  : 512*12288*2  =  12582912
    //   partial@ 16678912 : 8*512*2048*4 =  33554432
    //   Wm     @ 50233344 : 15*4M*2      = 125829120   (end ~176 MB)
    char* ws = (char*)d_ws;
    bf16*  xb      = (bf16*)ws;
    bf16*  w_inb   = (bf16*)(ws + 819200);
    bf16*  actsT   = (bf16*)(ws + 4096000);
    float* partial = (float*)(ws + 16678912);
    bf16*  Wm      = (bf16*)(ws + 50233344);

    prep_kernel<<<2000, 256, 0, stream>>>(x, w_in, xb, w_inb);
    wm_kernel<<<61440, 256, 0, stream>>>(W, M, Wm);

    // input layer: A=xb [512x800], B=w_inb [2048x800], z=4 chunks of 224
    gemm_kernel<<<dim3(16, 4, 4), 256, 0, stream>>>(
        xb, DINP, w_inb, DINP, partial, 224, DINP);
    epilogue_kernel<<<1024, 256, 0, stream>>>(partial, 4, b_in, 1.0f, actsT);

    // DAG layers: A = actsT [512 x 2048i] (slices 0..i-1), B = Wm layer block
    for (int i = 1; i < 6; i++) {
        int idx = i * (i - 1) / 2;
        const bf16* Bl = Wm + ((size_t)idx << 22);
        gemm_kernel<<<dim3(16, 4, 8), 256, 0, stream>>>(
            actsT, ACT_LD, Bl, N_SZ * i, partial, 256 * i, N_SZ * i);
        epilogue_kernel<<<1024, 256, 0, stream>>>(
            partial, 8, bL + (size_t)(i - 1) * N_SZ, (float)i,
            actsT + (size_t)i * N_SZ);
    }

    out_kernel<<<512, 64, 0, stream>>>(
        actsT + (size_t)4 * N_SZ, actsT + (size_t)5 * N_SZ,
        w1, b1, w2, b2, out);
}

// Round 3
// 714.176 us; speedup vs baseline: 1.2375x; 1.0016x over previous
//
#include <hip/hip_runtime.h>

typedef __bf16 bf16;
typedef __attribute__((ext_vector_type(8))) __bf16 bf16x8;
typedef __attribute__((ext_vector_type(4))) __bf16 bf16x4;
typedef __attribute__((ext_vector_type(4))) float floatx4;

#define B_SZ 512
#define N_SZ 2048
#define DIN  784
#define DINP 800      // 784 padded to multiple of 32
#define ACT_LD 12288  // actsT row stride: 6 slices x 2048

// async global->LDS, 16B per lane; HW scatters to ldsbase + lane*16
__device__ __forceinline__ void load_lds16(const bf16* g, bf16* l) {
    __builtin_amdgcn_global_load_lds(
        (const __attribute__((address_space(1))) void*)g,
        (__attribute__((address_space(3))) void*)l, 16, 0, 0);
}

// ---------------------------------------------------------------------------
// prep: x[512][784] -> xb[512][800] bf16 (zero pad), w_in[2048][784] -> w_inb
// ---------------------------------------------------------------------------
__global__ __launch_bounds__(256)
void prep_kernel(const float* __restrict__ x, const float* __restrict__ w_in,
                 bf16* __restrict__ xb, bf16* __restrict__ w_inb)
{
    int g = blockIdx.x * 256 + threadIdx.x;           // 512000 groups of 4
    const int GPR = DINP / 4;                         // 200 groups per row
    const float* src; bf16* dst; int row, c;
    if (g < B_SZ * GPR) {
        row = g / GPR; c = g - row * GPR;
        src = x + (size_t)row * DIN;  dst = xb + (size_t)row * DINP;
    } else {
        int h = g - B_SZ * GPR;
        row = h / GPR; c = h - row * GPR;
        src = w_in + (size_t)row * DIN;  dst = w_inb + (size_t)row * DINP;
    }
    int k = c * 4;
    floatx4 v = (floatx4){0.f, 0.f, 0.f, 0.f};
    if (k < DIN) v = *(const floatx4*)(src + k);      // 784 % 4 == 0
    bf16x4 o;
    o[0] = (bf16)v[0]; o[1] = (bf16)v[1]; o[2] = (bf16)v[2]; o[3] = (bf16)v[3];
    *(bf16x4*)(dst + k) = o;
}

// ---------------------------------------------------------------------------
// Input-layer GEMM (both operands bf16): 128x128 tile, BK=32, z K-chunks.
// ---------------------------------------------------------------------------
__global__ __launch_bounds__(256, 2)
void gemm_kernel(const bf16* __restrict__ A, int lda,
                 const bf16* __restrict__ Bm, int ldb,
                 float* __restrict__ partial,
                 int chunkK, int Ktot)
{
    __shared__ bf16 As[128 * 32];
    __shared__ bf16 Bs[128 * 32];

    const int t    = threadIdx.x;
    const int lane = t & 63, wave = t >> 6;
    const int wm   = (wave & 1) * 64, wn = (wave >> 1) * 64;
    const int l15  = lane & 15, quad = lane >> 4;
    const int n0   = blockIdx.x * 128, m0 = blockIdx.y * 128;
    const int s    = blockIdx.z;
    const int kb   = s * chunkK;
    const int ke   = (kb + chunkK < Ktot) ? (kb + chunkK) : Ktot;

    const int rA = wave * 16 + (lane >> 2);
    const int cA = (lane & 3) * 8;
    const bf16* pA0 = A  + (size_t)(m0 + rA) * lda + cA + kb;
    const bf16* pA1 = pA0 + (size_t)64 * lda;
    const bf16* pB0 = Bm + (size_t)(n0 + rA) * ldb + cA + kb;
    const bf16* pB1 = pB0 + (size_t)64 * ldb;
    bf16* dA0 = &As[wave * 512];  bf16* dA1 = &As[(wave + 4) * 512];
    bf16* dB0 = &Bs[wave * 512];  bf16* dB1 = &Bs[(wave + 4) * 512];

    floatx4 acc[4][4];
#pragma unroll
    for (int a = 0; a < 4; a++)
#pragma unroll
        for (int b = 0; b < 4; b++) acc[a][b] = (floatx4){0.f, 0.f, 0.f, 0.f};

    for (int k0 = kb; k0 < ke; k0 += 32) {
        __syncthreads();
        load_lds16(pA0, dA0);  load_lds16(pA1, dA1);
        load_lds16(pB0, dB0);  load_lds16(pB1, dB1);
        pA0 += 32; pA1 += 32; pB0 += 32; pB1 += 32;
        __syncthreads();

        bf16x8 af[4], bfr[4];
#pragma unroll
        for (int a = 0; a < 4; a++)
            af[a] = *(const bf16x8*)(&As[(wm + a * 16 + l15) * 32 + quad * 8]);
#pragma unroll
        for (int b = 0; b < 4; b++)
            bfr[b] = *(const bf16x8*)(&Bs[(wn + b * 16 + l15) * 32 + quad * 8]);
#pragma unroll
        for (int a = 0; a < 4; a++)
#pragma unroll
            for (int b = 0; b < 4; b++)
                acc[a][b] = __builtin_amdgcn_mfma_f32_16x16x32_bf16(af[a], bfr[b], acc[a][b], 0, 0, 0);
    }

    float* outp = partial + (size_t)s * (B_SZ * N_SZ);
#pragma unroll
    for (int a = 0; a < 4; a++)
#pragma unroll
        for (int b = 0; b < 4; b++)
#pragma unroll
            for (int r = 0; r < 4; r++) {
                int row = m0 + wm + a * 16 + quad * 4 + r;
                int col = n0 + wn + b * 16 + l15;
                outp[(size_t)row * N_SZ + col] = acc[a][b][r];
            }
}

// ---------------------------------------------------------------------------
// DAG GEMM with fused mask: out[b,m] = sum_k A[b,k] * (W*M)[m,k]_bf16
//   A: actsT bf16, row stride ACT_LD, cols 0..2048*i-1 (slices contiguous)
//   Wl/Ml: layer slab, pair j at offset j*4M; B[n][j*2048+kk] = Wl[j][n][kk]
// Tile: 256(M) x 64(N), BK=32. 4 waves, wave w = rows w*64..+63, all 64 cols.
// z = 8 K-chunks -> partial[s][512][2048]. W/M regs prefetched 1 step ahead.
// ---------------------------------------------------------------------------
__global__ __launch_bounds__(256, 2)
void dag_gemm_kernel(const bf16* __restrict__ A,
                     const float* __restrict__ Wl, const float* __restrict__ Ml,
                     float* __restrict__ partial,
                     int chunkK, int Ktot)
{
    __shared__ bf16 As[256 * 32];   // 16 KB
    __shared__ bf16 Bs[64 * 32];    //  4 KB

    const int t    = threadIdx.x;
    const int lane = t & 63, wave = t >> 6;
    const int l15  = lane & 15, quad = lane >> 4;
    const int n0   = blockIdx.x * 64, m0 = blockIdx.y * 256;
    const int s    = blockIdx.z;
    const int kb   = s * chunkK;
    const int ke   = kb + chunkK;             // K always divisible by 8*32

    // A staging: 4 issues/thread; issue l: row m0+l*64+wave*16+(lane>>2), col (lane&3)*8
    const int ar = wave * 16 + (lane >> 2);
    const int ac = (lane & 3) * 8;
    const bf16* pA0 = A + (size_t)(m0 +   0 + ar) * ACT_LD + kb + ac;
    const bf16* pA1 = A + (size_t)(m0 +  64 + ar) * ACT_LD + kb + ac;
    const bf16* pA2 = A + (size_t)(m0 + 128 + ar) * ACT_LD + kb + ac;
    const bf16* pA3 = A + (size_t)(m0 + 192 + ar) * ACT_LD + kb + ac;
    bf16* dA0 = &As[(  0 + wave * 16) * 32];
    bf16* dA1 = &As[( 64 + wave * 16) * 32];
    bf16* dA2 = &As[(128 + wave * 16) * 32];
    bf16* dA3 = &As[(192 + wave * 16) * 32];

    // B staging: thread covers B row br = t>>2 (0..63), k-segment bc = (t&3)*8
    const int br = t >> 2, bc = (t & 3) * 8;
    const size_t wrow = (size_t)(n0 + br) << 11;   // n*2048 within a pair

    floatx4 acc[4][4];
#pragma unroll
    for (int a = 0; a < 4; a++)
#pragma unroll
        for (int b = 0; b < 4; b++) acc[a][b] = (floatx4){0.f, 0.f, 0.f, 0.f};

    // prefetch W/M for first step
    floatx4 wr0, wr1, mr0, mr1;
    {
        int jj = kb >> 11, kk = kb & 2047;
        size_t o = ((size_t)jj << 22) + wrow + kk + bc;
        wr0 = *(const floatx4*)(Wl + o);  wr1 = *(const floatx4*)(Wl + o + 4);
        mr0 = *(const floatx4*)(Ml + o);  mr1 = *(const floatx4*)(Ml + o + 4);
    }

    for (int k0 = kb; k0 < ke; k0 += 32) {
        __syncthreads();
        load_lds16(pA0, dA0);  load_lds16(pA1, dA1);
        load_lds16(pA2, dA2);  load_lds16(pA3, dA3);
        pA0 += 32; pA1 += 32; pA2 += 32; pA3 += 32;

        bf16x8 o8;
        o8[0] = (bf16)(wr0[0] * mr0[0]); o8[1] = (bf16)(wr0[1] * mr0[1]);
        o8[2] = (bf16)(wr0[2] * mr0[2]); o8[3] = (bf16)(wr0[3] * mr0[3]);
        o8[4] = (bf16)(wr1[0] * mr1[0]); o8[5] = (bf16)(wr1[1] * mr1[1]);
        o8[6] = (bf16)(wr1[2] * mr1[2]); o8[7] = (bf16)(wr1[3] * mr1[3]);
        *(bf16x8*)(&Bs[br * 32 + bc]) = o8;

        if (k0 + 32 < ke) {                       // prefetch next step's W/M
            int kn = k0 + 32;
            int jj = kn >> 11, kk = kn & 2047;
            size_t o = ((size_t)jj << 22) + wrow + kk + bc;
            wr0 = *(const floatx4*)(Wl + o);  wr1 = *(const floatx4*)(Wl + o + 4);
            mr0 = *(const floatx4*)(Ml + o);  mr1 = *(const floatx4*)(Ml + o + 4);
        }
        __syncthreads();

        bf16x8 af[4], bfr[4];
#pragma unroll
        for (int a = 0; a < 4; a++)
            af[a] = *(const bf16x8*)(&As[(wave * 64 + a * 16 + l15) * 32 + quad * 8]);
#pragma unroll
        for (int b = 0; b < 4; b++)
            bfr[b] = *(const bf16x8*)(&Bs[(b * 16 + l15) * 32 + quad * 8]);
#pragma unroll
        for (int a = 0; a < 4; a++)
#pragma unroll
            for (int b = 0; b < 4; b++)
                acc[a][b] = __builtin_amdgcn_mfma_f32_16x16x32_bf16(af[a], bfr[b], acc[a][b], 0, 0, 0);
    }

    // C/D layout: col = lane&15, row = quad*4 + reg
    float* outp = partial + (size_t)s * (B_SZ * N_SZ);
#pragma unroll
    for (int a = 0; a < 4; a++)
#pragma unroll
        for (int b = 0; b < 4; b++)
#pragma unroll
            for (int r = 0; r < 4; r++) {
                int row = m0 + wave * 64 + a * 16 + quad * 4 + r;
                int col = n0 + b * 16 + l15;
                outp[(size_t)row * N_SZ + col] = acc[a][b][r];
            }
}

// ---------------------------------------------------------------------------
// epilogue: actsT[b][slice*2048+n] = bf16(relu(sum_s partial[s][b][n] + bscale*bias[n]))
// ---------------------------------------------------------------------------
__global__ __launch_bounds__(256)
void epilogue_kernel(const float* __restrict__ partial, int S,
                     const float* __restrict__ bias, float bscale,
                     bf16* __restrict__ actdst)   // = actsT + slice*2048
{
    int g = blockIdx.x * 256 + threadIdx.x;       // 262144 groups of 4
    size_t off = (size_t)g * 4;
    int b = (int)(off >> 11);
    int n = (int)(off & (N_SZ - 1));
    floatx4 v = *(const floatx4*)(partial + off);
    for (int s2 = 1; s2 < S; s2++)
        v += *(const floatx4*)(partial + (size_t)s2 * (B_SZ * N_SZ) + off);
    floatx4 bv = *(const floatx4*)(bias + n);
    bf16x4 o;
#pragma unroll
    for (int j = 0; j < 4; j++) {
        float xv = v[j] + bscale * bv[j];
        xv = xv > 0.f ? xv : 0.f;
        o[j] = (bf16)xv;
    }
    *(bf16x4*)(actdst + (size_t)b * ACT_LD + n) = o;
}

// ---------------------------------------------------------------------------
// output: out[b,c] = act5[b]·w1[c] + b1[c] + act4[b]·w2[c] + b2[c]
// ---------------------------------------------------------------------------
__global__ __launch_bounds__(64)
void out_kernel(const bf16* __restrict__ act4, const bf16* __restrict__ act5,
                const float* __restrict__ w1, const float* __restrict__ b1,
                const float* __restrict__ w2, const float* __restrict__ b2,
                float* __restrict__ out)
{
    int b = blockIdx.x, lane = threadIdx.x;
    float a5[32], a4[32];
#pragma unroll
    for (int rep = 0; rep < 4; rep++) {
        bf16x8 v5 = *(const bf16x8*)(act5 + (size_t)b * ACT_LD + rep * 512 + lane * 8);
        bf16x8 v4 = *(const bf16x8*)(act4 + (size_t)b * ACT_LD + rep * 512 + lane * 8);
#pragma unroll
        for (int j = 0; j < 8; j++) {
            a5[rep * 8 + j] = (float)v5[j];
            a4[rep * 8 + j] = (float)v4[j];
        }
    }
    for (int c = 0; c < 10; c++) {
        float d = 0.f;
#pragma unroll
        for (int rep = 0; rep < 4; rep++) {
            floatx4 wa = *(const floatx4*)(w1 + (size_t)c * N_SZ + rep * 512 + lane * 8);
            floatx4 wb = *(const floatx4*)(w1 + (size_t)c * N_SZ + rep * 512 + lane * 8 + 4);
            floatx4 va = *(const floatx4*)(w2 + (size_t)c * N_SZ + rep * 512 + lane * 8);
            floatx4 vb = *(const floatx4*)(w2 + (size_t)c * N_SZ + rep * 512 + lane * 8 + 4);
#pragma unroll
            for (int j = 0; j < 4; j++) {
                d += a5[rep * 8 + j] * wa[j] + a4[rep * 8 + j] * va[j];
                d += a5[rep * 8 + 4 + j] * wb[j] + a4[rep * 8 + 4 + j] * vb[j];
            }
        }
        for (int off = 32; off > 0; off >>= 1) d += __shfl_down(d, off);
        if (lane == 0) out[b * 10 + c] = d + b1[c] + b2[c];
    }
}

// ---------------------------------------------------------------------------
extern "C" void kernel_launch(void* const* d_in, const int* in_sizes, int n_in,
                              void* d_out, int out_size, void* d_ws, size_t ws_size,
                              hipStream_t stream)
{
    const float* x    = (const float*)d_in[0];
    const float* w_in = (const float*)d_in[1];
    const float* b_in = (const float*)d_in[2];
    const float* W    = (const float*)d_in[3];
    const float* M    = (const float*)d_in[4];
    const float* bL   = (const float*)d_in[5];
    const float* w1   = (const float*)d_in[6];
    const float* b1   = (const float*)d_in[7];
    const float* w2   = (const float*)d_in[8];
    const float* b2   = (const float*)d_in[9];
    float* out = (float*)d_out;

    // workspace layout (all 16B-aligned):
    //   xb     @ 0        : 512*800*2    =    819200
    //   w_inb  @ 819200   : 2048*800*2   =   3276800
    //   actsT  @ 4096000  : 512*12288*2  =  12582912
    //   partial@ 16678912 : 8*512*2048*4 =  33554432   (end ~50 MB)
    char* ws = (char*)d_ws;
    bf16*  xb      = (bf16*)ws;
    bf16*  w_inb   = (bf16*)(ws + 819200);
    bf16*  actsT   = (bf16*)(ws + 4096000);
    float* partial = (float*)(ws + 16678912);

    prep_kernel<<<2000, 256, 0, stream>>>(x, w_in, xb, w_inb);

    // input layer: A=xb [512x800], B=w_inb [2048x800], z=4 chunks of 224
    gemm_kernel<<<dim3(16, 4, 4), 256, 0, stream>>>(
        xb, DINP, w_inb, DINP, partial, 224, DINP);
    epilogue_kernel<<<1024, 256, 0, stream>>>(partial, 4, b_in, 1.0f, actsT);

    // DAG layers: fused W*M staging; grid (n=32, m=2, z=8) = 512 blocks
    for (int i = 1; i < 6; i++) {
        int idx = i * (i - 1) / 2;
        const float* Wl = W + ((size_t)idx << 22);
        const float* Ml = M + ((size_t)idx << 22);
        dag_gemm_kernel<<<dim3(32, 2, 8), 256, 0, stream>>>(
            actsT, Wl, Ml, partial, 256 * i, 2048 * i);
        epilogue_kernel<<<1024, 256, 0, stream>>>(
            partial, 8, bL + (size_t)(i - 1) * N_SZ, (float)i,
            actsT + (size_t)i * N_SZ);
    }

    out_kernel<<<512, 64, 0, stream>>>(
        actsT + (size_t)4 * N_SZ, actsT + (size_t)5 * N_SZ,
        w1, b1, w2, b2, out);
}

// Round 4
// 691.499 us; speedup vs baseline: 1.2781x; 1.0328x over previous
//
#include <hip/hip_runtime.h>

typedef __bf16 bf16;
typedef __attribute__((ext_vector_type(8))) __bf16 bf16x8;
typedef __attribute__((ext_vector_type(4))) __bf16 bf16x4;
typedef __attribute__((ext_vector_type(4))) float floatx4;

#define B_SZ 512
#define N_SZ 2048
#define DIN  784
#define DINP 800      // 784 padded to multiple of 32
#define ACT_LD 12288  // actsT row stride: 6 slices x 2048

// async global->LDS, 16B per lane (input-layer gemm only)
__device__ __forceinline__ void load_lds16(const bf16* g, bf16* l) {
    __builtin_amdgcn_global_load_lds(
        (const __attribute__((address_space(1))) void*)g,
        (__attribute__((address_space(3))) void*)l, 16, 0, 0);
}

// ---------------------------------------------------------------------------
// prep: x[512][784] -> xb[512][800] bf16 (zero pad), w_in[2048][784] -> w_inb
// ---------------------------------------------------------------------------
__global__ __launch_bounds__(256)
void prep_kernel(const float* __restrict__ x, const float* __restrict__ w_in,
                 bf16* __restrict__ xb, bf16* __restrict__ w_inb)
{
    int g = blockIdx.x * 256 + threadIdx.x;           // 512000 groups of 4
    const int GPR = DINP / 4;                         // 200 groups per row
    const float* src; bf16* dst; int row, c;
    if (g < B_SZ * GPR) {
        row = g / GPR; c = g - row * GPR;
        src = x + (size_t)row * DIN;  dst = xb + (size_t)row * DINP;
    } else {
        int h = g - B_SZ * GPR;
        row = h / GPR; c = h - row * GPR;
        src = w_in + (size_t)row * DIN;  dst = w_inb + (size_t)row * DINP;
    }
    int k = c * 4;
    floatx4 v = (floatx4){0.f, 0.f, 0.f, 0.f};
    if (k < DIN) v = *(const floatx4*)(src + k);      // 784 % 4 == 0
    bf16x4 o;
    o[0] = (bf16)v[0]; o[1] = (bf16)v[1]; o[2] = (bf16)v[2]; o[3] = (bf16)v[3];
    *(bf16x4*)(dst + k) = o;
}

// ---------------------------------------------------------------------------
// Input-layer GEMM (both operands bf16): 128x128 tile, BK=32, z K-chunks.
// ---------------------------------------------------------------------------
__global__ __launch_bounds__(256, 2)
void gemm_kernel(const bf16* __restrict__ A, int lda,
                 const bf16* __restrict__ Bm, int ldb,
                 float* __restrict__ partial,
                 int chunkK, int Ktot)
{
    __shared__ bf16 As[128 * 32];
    __shared__ bf16 Bs[128 * 32];

    const int t    = threadIdx.x;
    const int lane = t & 63, wave = t >> 6;
    const int wm   = (wave & 1) * 64, wn = (wave >> 1) * 64;
    const int l15  = lane & 15, quad = lane >> 4;
    const int n0   = blockIdx.x * 128, m0 = blockIdx.y * 128;
    const int s    = blockIdx.z;
    const int kb   = s * chunkK;
    const int ke   = (kb + chunkK < Ktot) ? (kb + chunkK) : Ktot;

    const int rA = wave * 16 + (lane >> 2);
    const int cA = (lane & 3) * 8;
    const bf16* pA0 = A  + (size_t)(m0 + rA) * lda + cA + kb;
    const bf16* pA1 = pA0 + (size_t)64 * lda;
    const bf16* pB0 = Bm + (size_t)(n0 + rA) * ldb + cA + kb;
    const bf16* pB1 = pB0 + (size_t)64 * ldb;
    bf16* dA0 = &As[wave * 512];  bf16* dA1 = &As[(wave + 4) * 512];
    bf16* dB0 = &Bs[wave * 512];  bf16* dB1 = &Bs[(wave + 4) * 512];

    floatx4 acc[4][4];
#pragma unroll
    for (int a = 0; a < 4; a++)
#pragma unroll
        for (int b = 0; b < 4; b++) acc[a][b] = (floatx4){0.f, 0.f, 0.f, 0.f};

    for (int k0 = kb; k0 < ke; k0 += 32) {
        __syncthreads();
        load_lds16(pA0, dA0);  load_lds16(pA1, dA1);
        load_lds16(pB0, dB0);  load_lds16(pB1, dB1);
        pA0 += 32; pA1 += 32; pB0 += 32; pB1 += 32;
        __syncthreads();

        bf16x8 af[4], bfr[4];
#pragma unroll
        for (int a = 0; a < 4; a++)
            af[a] = *(const bf16x8*)(&As[(wm + a * 16 + l15) * 32 + quad * 8]);
#pragma unroll
        for (int b = 0; b < 4; b++)
            bfr[b] = *(const bf16x8*)(&Bs[(wn + b * 16 + l15) * 32 + quad * 8]);
#pragma unroll
        for (int a = 0; a < 4; a++)
#pragma unroll
            for (int b = 0; b < 4; b++)
                acc[a][b] = __builtin_amdgcn_mfma_f32_16x16x32_bf16(af[a], bfr[b], acc[a][b], 0, 0, 0);
    }

    float* outp = partial + (size_t)s * (B_SZ * N_SZ);
#pragma unroll
    for (int a = 0; a < 4; a++)
#pragma unroll
        for (int b = 0; b < 4; b++)
#pragma unroll
            for (int r = 0; r < 4; r++) {
                int row = m0 + wm + a * 16 + quad * 4 + r;
                int col = n0 + wn + b * 16 + l15;
                outp[(size_t)row * N_SZ + col] = acc[a][b][r];
            }
}

// ---------------------------------------------------------------------------
// DAG GEMM, fused mask, register-staged + LDS double buffer (1 barrier/step).
// out[b,m] = sum_k A[b,k] * (W*M)[m,k]; A bf16 (stride ACT_LD), W/M fp32.
// Tile 256(M batch) x 64(N out), BK=32, 4 waves, z=8 K-chunks.
// NO global_load_lds here: plain VGPR loads survive __syncthreads(), giving
// cross-barrier prefetch (the R3 version's global_load_lds forced a
// vmcnt(0) drain at every barrier, exposing full HBM latency per k-step).
// ---------------------------------------------------------------------------
__global__ __launch_bounds__(256, 2)
void dag_gemm_kernel(const bf16* __restrict__ A,
                     const float* __restrict__ Wl, const float* __restrict__ Ml,
                     float* __restrict__ partial,
                     int chunkK)
{
    __shared__ bf16 As[2][256 * 32];   // 16 KB x2
    __shared__ bf16 Bs[2][64 * 32];    //  4 KB x2

    const int t    = threadIdx.x;
    const int lane = t & 63, wave = t >> 6;
    const int l15  = lane & 15, quad = lane >> 4;
    const int n0   = blockIdx.x * 64, m0 = blockIdx.y * 256;
    const int kb   = blockIdx.z * chunkK;
    const int ke   = kb + chunkK;              // chunkK = 256*i, mult of 64

    // A staging: 4 rows per thread, spaced 64 apart
    const int ar = wave * 16 + (lane >> 2);    // 0..63
    const int ac = (lane & 3) * 8;             // k-seg (16 B)
    // B staging: thread covers B row br (0..63), k-seg bc
    const int br = t >> 2, bc = (t & 3) * 8;
    const size_t wrow = (size_t)(n0 + br) << 11;

    floatx4 acc[4][4];
#pragma unroll
    for (int a = 0; a < 4; a++)
#pragma unroll
        for (int b = 0; b < 4; b++) acc[a][b] = (floatx4){0.f, 0.f, 0.f, 0.f};

    bf16x8 a0, a1, a2, a3;                     // staged A regs
    floatx4 wv0, wv1, mv0, mv1;                // staged W/M regs

    auto load_regs = [&](int k) {
        const bf16* ap = A + (size_t)(m0 + ar) * ACT_LD + k + ac;
        a0 = *(const bf16x8*)(ap);
        a1 = *(const bf16x8*)(ap + (size_t)64  * ACT_LD);
        a2 = *(const bf16x8*)(ap + (size_t)128 * ACT_LD);
        a3 = *(const bf16x8*)(ap + (size_t)192 * ACT_LD);
        int jj = k >> 11, kk = k & 2047;
        size_t o = ((size_t)jj << 22) + wrow + kk + bc;
        wv0 = *(const floatx4*)(Wl + o);  wv1 = *(const floatx4*)(Wl + o + 4);
        mv0 = *(const floatx4*)(Ml + o);  mv1 = *(const floatx4*)(Ml + o + 4);
    };

    auto do_step = [&](int buf, int knext, bool pref) {
        // pack B = bf16(W*M) and commit staged regs to LDS[buf]
        bf16x8 o8;
        o8[0] = (bf16)(wv0[0] * mv0[0]); o8[1] = (bf16)(wv0[1] * mv0[1]);
        o8[2] = (bf16)(wv0[2] * mv0[2]); o8[3] = (bf16)(wv0[3] * mv0[3]);
        o8[4] = (bf16)(wv1[0] * mv1[0]); o8[5] = (bf16)(wv1[1] * mv1[1]);
        o8[6] = (bf16)(wv1[2] * mv1[2]); o8[7] = (bf16)(wv1[3] * mv1[3]);
        *(bf16x8*)(&Bs[buf][br * 32 + bc]) = o8;
        *(bf16x8*)(&As[buf][(ar +   0) * 32 + ac]) = a0;
        *(bf16x8*)(&As[buf][(ar +  64) * 32 + ac]) = a1;
        *(bf16x8*)(&As[buf][(ar + 128) * 32 + ac]) = a2;
        *(bf16x8*)(&As[buf][(ar + 192) * 32 + ac]) = a3;
        if (pref) load_regs(knext);            // in flight across barrier
        __syncthreads();
        bf16x8 af[4], bfr[4];
#pragma unroll
        for (int a = 0; a < 4; a++)
            af[a] = *(const bf16x8*)(&As[buf][(wave * 64 + a * 16 + l15) * 32 + quad * 8]);
#pragma unroll
        for (int b = 0; b < 4; b++)
            bfr[b] = *(const bf16x8*)(&Bs[buf][(b * 16 + l15) * 32 + quad * 8]);
#pragma unroll
        for (int a = 0; a < 4; a++)
#pragma unroll
            for (int b = 0; b < 4; b++)
                acc[a][b] = __builtin_amdgcn_mfma_f32_16x16x32_bf16(af[a], bfr[b], acc[a][b], 0, 0, 0);
    };

    load_regs(kb);
    for (int k0 = kb; k0 < ke; k0 += 64) {
        do_step(0, k0 + 32, true);                  // k0+32 < ke always
        do_step(1, k0 + 64, (k0 + 64) < ke);
    }

    // C/D layout: col = lane&15, row = quad*4 + reg
    float* outp = partial + (size_t)blockIdx.z * (B_SZ * N_SZ);
#pragma unroll
    for (int a = 0; a < 4; a++)
#pragma unroll
        for (int b = 0; b < 4; b++)
#pragma unroll
            for (int r = 0; r < 4; r++) {
                int row = m0 + wave * 64 + a * 16 + quad * 4 + r;
                int col = n0 + b * 16 + l15;
                outp[(size_t)row * N_SZ + col] = acc[a][b][r];
            }
}

// ---------------------------------------------------------------------------
// epilogue: actsT[b][slice*2048+n] = bf16(relu(sum_s partial[s][b][n] + bscale*bias[n]))
// ---------------------------------------------------------------------------
__global__ __launch_bounds__(256)
void epilogue_kernel(const float* __restrict__ partial, int S,
                     const float* __restrict__ bias, float bscale,
                     bf16* __restrict__ actdst)   // = actsT + slice*2048
{
    int g = blockIdx.x * 256 + threadIdx.x;       // 262144 groups of 4
    size_t off = (size_t)g * 4;
    int b = (int)(off >> 11);
    int n = (int)(off & (N_SZ - 1));
    floatx4 v = *(const floatx4*)(partial + off);
    for (int s2 = 1; s2 < S; s2++)
        v += *(const floatx4*)(partial + (size_t)s2 * (B_SZ * N_SZ) + off);
    floatx4 bv = *(const floatx4*)(bias + n);
    bf16x4 o;
#pragma unroll
    for (int j = 0; j < 4; j++) {
        float xv = v[j] + bscale * bv[j];
        xv = xv > 0.f ? xv : 0.f;
        o[j] = (bf16)xv;
    }
    *(bf16x4*)(actdst + (size_t)b * ACT_LD + n) = o;
}

// ---------------------------------------------------------------------------
// output: out[b,c] = act5[b]·w1[c] + b1[c] + act4[b]·w2[c] + b2[c]
// ---------------------------------------------------------------------------
__global__ __launch_bounds__(64)
void out_kernel(const bf16* __restrict__ act4, const bf16* __restrict__ act5,
                const float* __restrict__ w1, const float* __restrict__ b1,
                const float* __restrict__ w2, const float* __restrict__ b2,
                float* __restrict__ out)
{
    int b = blockIdx.x, lane = threadIdx.x;
    float a5[32], a4[32];
#pragma unroll
    for (int rep = 0; rep < 4; rep++) {
        bf16x8 v5 = *(const bf16x8*)(act5 + (size_t)b * ACT_LD + rep * 512 + lane * 8);
        bf16x8 v4 = *(const bf16x8*)(act4 + (size_t)b * ACT_LD + rep * 512 + lane * 8);
#pragma unroll
        for (int j = 0; j < 8; j++) {
            a5[rep * 8 + j] = (float)v5[j];
            a4[rep * 8 + j] = (float)v4[j];
        }
    }
    for (int c = 0; c < 10; c++) {
        float d = 0.f;
#pragma unroll
        for (int rep = 0; rep < 4; rep++) {
            floatx4 wa = *(const floatx4*)(w1 + (size_t)c * N_SZ + rep * 512 + lane * 8);
            floatx4 wb = *(const floatx4*)(w1 + (size_t)c * N_SZ + rep * 512 + lane * 8 + 4);
            floatx4 va = *(const floatx4*)(w2 + (size_t)c * N_SZ + rep * 512 + lane * 8);
            floatx4 vb = *(const floatx4*)(w2 + (size_t)c * N_SZ + rep * 512 + lane * 8 + 4);
#pragma unroll
            for (int j = 0; j < 4; j++) {
                d += a5[rep * 8 + j] * wa[j] + a4[rep * 8 + j] * va[j];
                d += a5[rep * 8 + 4 + j] * wb[j] + a4[rep * 8 + 4 + j] * vb[j];
            }
        }
        for (int off = 32; off > 0; off >>= 1) d += __shfl_down(d, off);
        if (lane == 0) out[b * 10 + c] = d + b1[c] + b2[c];
    }
}

// ---------------------------------------------------------------------------
extern "C" void kernel_launch(void* const* d_in, const int* in_sizes, int n_in,
                              void* d_out, int out_size, void* d_ws, size_t ws_size,
                              hipStream_t stream)
{
    const float* x    = (const float*)d_in[0];
    const float* w_in = (const float*)d_in[1];
    const float* b_in = (const float*)d_in[2];
    const float* W    = (const float*)d_in[3];
    const float* M    = (const float*)d_in[4];
    const float* bL   = (const float*)d_in[5];
    const float* w1   = (const float*)d_in[6];
    const float* b1   = (const float*)d_in[7];
    const float* w2   = (const float*)d_in[8];
    const float* b2   = (const float*)d_in[9];
    float* out = (float*)d_out;

    // workspace layout (all 16B-aligned):
    //   xb     @ 0        : 512*800*2    =    819200
    //   w_inb  @ 819200   : 2048*800*2   =   3276800
    //   actsT  @ 4096000  : 512*12288*2  =  12582912
    //   partial@ 16678912 : 8*512*2048*4 =  33554432   (end ~50 MB)
    char* ws = (char*)d_ws;
    bf16*  xb      = (bf16*)ws;
    bf16*  w_inb   = (bf16*)(ws + 819200);
    bf16*  actsT   = (bf16*)(ws + 4096000);
    float* partial = (float*)(ws + 16678912);

    prep_kernel<<<2000, 256, 0, stream>>>(x, w_in, xb, w_inb);

    // input layer: A=xb [512x800], B=w_inb [2048x800], z=4 chunks of 224
    gemm_kernel<<<dim3(16, 4, 4), 256, 0, stream>>>(
        xb, DINP, w_inb, DINP, partial, 224, DINP);
    epilogue_kernel<<<1024, 256, 0, stream>>>(partial, 4, b_in, 1.0f, actsT);

    // DAG layers: fused W*M staging; grid (n=32, m=2, z=8) = 512 blocks
    for (int i = 1; i < 6; i++) {
        int idx = i * (i - 1) / 2;
        const float* Wl = W + ((size_t)idx << 22);
        const float* Ml = M + ((size_t)idx << 22);
        dag_gemm_kernel<<<dim3(32, 2, 8), 256, 0, stream>>>(
            actsT, Wl, Ml, partial, 256 * i);
        epilogue_kernel<<<1024, 256, 0, stream>>>(
            partial, 8, bL + (size_t)(i - 1) * N_SZ, (float)i,
            actsT + (size_t)i * N_SZ);
    }

    out_kernel<<<512, 64, 0, stream>>>(
        actsT + (size_t)4 * N_SZ, actsT + (size_t)5 * N_SZ,
        w1, b1, w2, b2, out);
}